// Round 1
// baseline (137.157 us; speedup 1.0000x reference)
//
#include <hip/hip_runtime.h>

#define B_SZ 16
#define T_SZ 1024
#define D_SZ 384
#define MAX_DUR 4
#define OUT_LEN (T_SZ * MAX_DUR)            // 4096 frames per sample
#define C4 (D_SZ / 4)                       // 96 float4 per frame
#define PER_SAMPLE_F4 (OUT_LEN * C4)        // 393216 float4 per sample
#define BLOCKS_PER_SAMPLE 128               // 128 blocks per sample
#define FRAMES_PER_BLOCK 32                 // 32 frames * 96 = 3072 float4 per block
#define F4_PER_BLOCK (FRAMES_PER_BLOCK * C4)  // 3072
#define ITERS (F4_PER_BLOCK / 256)          // 12

typedef float f32x4 __attribute__((ext_vector_type(4)));

// v2: frame-aligned blocks (exactly 32 output frames each), tiny 32-entry LDS map,
// shuffle-scan (1 barrier), windowed scatter, nontemporal output stream.
// Grid = 2048 blocks = exactly 8 blocks/CU at <=64 VGPR -> one scheduling wave,
// 32 waves/CU to hide the gather latency.
__global__ __launch_bounds__(256, 8) void lenreg_v2(const f32x4* __restrict__ xs4,
                                                    const int* __restrict__ ds,
                                                    f32x4* __restrict__ out4) {
    __shared__ int map_s[FRAMES_PER_BLOCK];   // frame -> src float4 base (within sample), -1 = pad
    __shared__ int wsum[4];                   // per-wave duration totals

    const int tid  = threadIdx.x;
    const int lane = tid & 63;
    const int w    = tid >> 6;
    const int b    = blockIdx.x >> 7;                   // / BLOCKS_PER_SAMPLE
    const int blk  = blockIdx.x & (BLOCKS_PER_SAMPLE - 1);
    const int w0   = blk * FRAMES_PER_BLOCK;            // first frame owned by this block

    // --- load this thread's 4 token durations (4 KB per block, L2-hot) ---
    const int4 v = ((const int4*)(ds + b * T_SZ))[tid];
    const int s0 = v.x;
    const int s1 = s0 + v.y;
    const int s2 = s1 + v.z;
    const int s3 = s2 + v.w;

    // --- wave-level inclusive scan of per-thread totals (no barriers) ---
    int incl = s3;
    #pragma unroll
    for (int off = 1; off < 64; off <<= 1) {
        const int n = __shfl_up(incl, off, 64);
        if (lane >= off) incl += n;
    }
    if (lane == 63) wsum[w] = incl;
    if (tid < FRAMES_PER_BLOCK) map_s[tid] = -1;        // default: pad
    __syncthreads();

    int woff = 0;
    #pragma unroll
    for (int i = 0; i < 4; ++i) woff += (i < w) ? wsum[i] : 0;
    const int excl = woff + (incl - s3);                // frames before this thread's tokens

    // --- scatter: this thread's token frame-ranges clamped to [w0, w0+32) ---
    {
        const int srcBase = 4 * tid * C4;               // float4 base of token 4*tid (within sample)
        const int w1 = w0 + FRAMES_PER_BLOCK;
        int st = excl;
        int en = excl + s0;
        for (int t = (st > w0 ? st : w0); t < (en < w1 ? en : w1); ++t) map_s[t - w0] = srcBase;
        st = en; en = excl + s1;
        for (int t = (st > w0 ? st : w0); t < (en < w1 ? en : w1); ++t) map_s[t - w0] = srcBase + C4;
        st = en; en = excl + s2;
        for (int t = (st > w0 ? st : w0); t < (en < w1 ? en : w1); ++t) map_s[t - w0] = srcBase + 2 * C4;
        st = en; en = excl + s3;
        for (int t = (st > w0 ? st : w0); t < (en < w1 ? en : w1); ++t) map_s[t - w0] = srcBase + 3 * C4;
    }
    __syncthreads();

    // --- copy phase: 3072 float4 for this block, streaming nontemporal stores ---
    const f32x4* __restrict__ xsb  = xs4 + (size_t)b * (T_SZ * C4);
    f32x4* __restrict__ outp = out4 + (size_t)b * PER_SAMPLE_F4 + (size_t)w0 * C4;

    #pragma unroll 4
    for (int k = 0; k < ITERS; ++k) {
        const unsigned l   = (unsigned)(k * 256 + tid);
        const unsigned f   = l / 96u;                   // frame within block window (magic-mul)
        const unsigned col = l - f * 96u;
        const int s = map_s[f];                         // <=2 distinct values per wave (broadcast)
        f32x4 o = {0.0f, 0.0f, 0.0f, 0.0f};             // PAD_VALUE
        if (s >= 0) o = xsb[s + col];
        __builtin_nontemporal_store(o, outp + l);
    }
}

extern "C" void kernel_launch(void* const* d_in, const int* in_sizes, int n_in,
                              void* d_out, int out_size, void* d_ws, size_t ws_size,
                              hipStream_t stream) {
    const f32x4* xs4 = (const f32x4*)d_in[0];
    const int*   ds  = (const int*)d_in[1];
    f32x4*       out4 = (f32x4*)d_out;

    lenreg_v2<<<B_SZ * BLOCKS_PER_SAMPLE, 256, 0, stream>>>(xs4, ds, out4);
}